// Round 4
// baseline (118.132 us; speedup 1.0000x reference)
//
#include <hip/hip_runtime.h>

#define FEATS 768
#define NHEAD 12
#define HD    64
#define SEQ   1024
#define NB    8
#define MROWS (NB*SEQ)      // 8192
#define NQK   (2*FEATS)     // 1536
#define QKVN  (3*FEATS)     // 2304
#define QSC   0.0520616136f // (1/sqrt(768)) * log2(e), folded into Q at GEMM1 epilogue

typedef __attribute__((ext_vector_type(8))) __bf16          bf16x8;
typedef __attribute__((ext_vector_type(4))) __bf16          bf16x4;
typedef __attribute__((ext_vector_type(4))) unsigned short  us4;
typedef __attribute__((ext_vector_type(4))) float           f32x4;

__device__ __forceinline__ unsigned short f2bf(float f) {
  union { float f; unsigned u; } v; v.f = f;
  return (unsigned short)((v.u + 0x7fffu + ((v.u >> 16) & 1u)) >> 16);  // RNE
}

__device__ __forceinline__ void gload_lds16(const void* g, void* l) {
  __builtin_amdgcn_global_load_lds(
      (const __attribute__((address_space(1))) void*)g,
      (__attribute__((address_space(3))) void*)l, 16, 0, 0);
}

// ---------------- fused casts (at BW ceiling -- unchanged) ----------------
__global__ void cast_all(const float* __restrict__ x,
                         const float* __restrict__ Wq, const float* __restrict__ Wk,
                         const float* __restrict__ Wv, const float* __restrict__ Wo,
                         const float* __restrict__ bq, const float* __restrict__ bk,
                         const float* __restrict__ bv,
                         unsigned short* __restrict__ Xbf,
                         unsigned short* __restrict__ Wcat,
                         unsigned short* __restrict__ Wobf,
                         float* __restrict__ bcat) {
  int blk = blockIdx.x;
  if (blk < 6144) {
    int i = blk * 256 + threadIdx.x;
    f32x4 v = ((const f32x4*)x)[i];
    us4 o;
    o[0] = f2bf(v[0]); o[1] = f2bf(v[1]); o[2] = f2bf(v[2]); o[3] = f2bf(v[3]);
    ((us4*)Xbf)[i] = o;
  } else if (blk < 8448) {
    int bb = blk - 6144;
    int mtx = bb / 576;
    int i = (bb % 576) * 256 + threadIdx.x;
    const float* src = (mtx == 0) ? Wq : (mtx == 1) ? Wk : (mtx == 2) ? Wv : Wo;
    f32x4 v = ((const f32x4*)src)[i];
    us4 o;
    o[0] = f2bf(v[0]); o[1] = f2bf(v[1]); o[2] = f2bf(v[2]); o[3] = f2bf(v[3]);
    if (mtx < 3) ((us4*)Wcat)[mtx * 147456 + i] = o;
    else         ((us4*)Wobf)[i] = o;
  } else {
    int i = (blk - 8448) * 256 + threadIdx.x;
    if (i < QKVN)
      bcat[i] = (i < FEATS) ? bq[i] : (i < 2*FEATS ? bk[i-FEATS] : bv[i-2*FEATS]);
  }
}

// read-side LDS swizzle (R7-R10 measured: 0 bank conflicts)
#define FOFF(row) ((row)*64 + (((g) ^ (((row) >> 1) & 3)) << 4))

// ---------------- GEMM1: 128x192 tile, 768 blocks, 3-buf counted-vmcnt pipeline ----
// QKV = Xbf * Wcat^T + bcat. ni 0..3 -> Q (pre-scaled by QSC), 4..7 -> K, 8..11 -> V^T.
// V^T key columns are PERMUTED within each 64-key tile (bit-permutation c(r)) so the
// attention PV B-operand needs no cross-lane redistribution (see attn_kernel).
// T4 schedule: 2 tiles in flight, wait vmcnt(5) (t+1 landed, t+2 in flight) -- never
// drain to 0 in the main loop. Triple-buffered LDS (60KB -> 2 blocks/CU).
__global__ __launch_bounds__(256, 2) void gemm1_bt(
    const unsigned short* __restrict__ A,
    const unsigned short* __restrict__ B,
    const float* __restrict__ bias,
    unsigned short* __restrict__ QKo,
    unsigned short* __restrict__ VTo)
{
  __shared__ __align__(16) char Al[3 * 8192];    // [buf][128 rows][64B]
  __shared__ __align__(16) char Bl[3 * 12288];   // [buf][192 rows][64B]

  const int tid  = threadIdx.x;
  const int lane = tid & 63;
  const int w    = tid >> 6;
  const int l15  = lane & 15;
  const int g    = lane >> 4;
  const int wm   = (w >> 1) * 64;
  const int wn   = (w & 1) * 96;

  const int id  = blockIdx.x;            // 768 = 8 xcd * (8 mi * 12 ni)
  const int xcd = id & 7;
  const int j   = id >> 3;
  const int mi  = xcd * 8 + (j & 7);
  const int ni  = j >> 3;                // 0..11
  const int mbase = mi * 128;
  const int nbase = ni * 192;

  const int trow  = tid >> 2;
  const int sslot = ((tid & 3) ^ ((tid >> 3) & 3)) * 8;
  const unsigned short* Ag = A + (size_t)(mbase + trow) * 768 + sslot;
  const unsigned short* Bg = B + (size_t)(nbase + trow) * 768 + sslot;

  auto STAGE = [&](int buf, int t) {
    const unsigned short* sa = Ag + t * 32;
    const unsigned short* sb = Bg + t * 32;
    char* da = Al + buf * 8192  + tid * 16;
    char* db = Bl + buf * 12288 + tid * 16;
    gload_lds16(sa,            da);
    gload_lds16(sa + 64*768,   da + 4096);
    gload_lds16(sb,            db);
    gload_lds16(sb + 64*768,   db + 4096);
    gload_lds16(sb + 128*768,  db + 8192);
  };

  f32x4 acc[4][6] = {};

  STAGE(0, 0);
  STAGE(1, 1);
  asm volatile("s_waitcnt vmcnt(5)" ::: "memory");   // t=0 landed; t=1 in flight
  __builtin_amdgcn_s_barrier();

  for (int t = 0; t < 24; t++) {
    if (t < 22) STAGE((t + 2) % 3, t + 2);           // issue early: 2 tiles in flight

    const char* Ab = Al + (t % 3) * 8192;
    const char* Bb = Bl + (t % 3) * 12288;
    bf16x8 af[4];
#pragma unroll
    for (int mf = 0; mf < 4; mf++) {
      const int row = wm + mf*16 + l15;
      af[mf] = *(const bf16x8*)(Ab + FOFF(row));
    }
    __builtin_amdgcn_s_setprio(1);
#pragma unroll
    for (int nf = 0; nf < 6; nf++) {
      const int row = wn + nf*16 + l15;
      bf16x8 bfv = *(const bf16x8*)(Bb + FOFF(row));
#pragma unroll
      for (int mf = 0; mf < 4; mf++)
        acc[mf][nf] = __builtin_amdgcn_mfma_f32_16x16x32_bf16(af[mf], bfv, acc[mf][nf], 0, 0, 0);
    }
    __builtin_amdgcn_s_setprio(0);

    if (t < 23) {
      if (t < 22) asm volatile("s_waitcnt vmcnt(5)" ::: "memory");  // t+1 done, t+2 in flight
      else        asm volatile("s_waitcnt vmcnt(0)" ::: "memory");  // last prefetch drains
      __builtin_amdgcn_s_barrier();
    }
  }

  // epilogue: D layout col = lane&15, row = (lane>>4)*4 + reg (m89-verified)
  const bool isQK = (ni < 8);            // block-uniform
  const float osc = (ni < 4) ? QSC : 1.0f;   // Q pre-scale (block-uniform)
#pragma unroll
  for (int mf = 0; mf < 4; mf++)
#pragma unroll
    for (int nf = 0; nf < 6; nf++) {
      const int col  = nbase + wn + nf*16 + l15;
      const float bb = bias[col];
      const int row0 = mbase + wm + mf*16 + g*4;
      if (isQK) {
#pragma unroll
        for (int r = 0; r < 4; r++)
          QKo[(size_t)(row0 + r)*NQK + col] = f2bf((acc[mf][nf][r] + bb) * osc);
      } else {
        const int c  = col - NQK;
        const int hh = c >> 6, dd = c & 63;
        const int bI = row0 >> 10, n0 = row0 & 1023;
        // key-column bit-permutation within the 64-key tile:
        // r = [b5b4=nf | b3b2=g | b1b0=rr] -> c = [b5 | b3b2 | b4 | b1b0]
        const int rl  = n0 & 63;   // rr bits are 0 here (n0 multiple of 4)
        const int cp  = ((rl >> 5) << 5) | (((rl >> 2) & 3) << 3) | (((rl >> 4) & 1) << 2);
        const int n0p = (n0 & ~63) | cp;
        us4 o;
#pragma unroll
        for (int r = 0; r < 4; r++) o[r] = f2bf(acc[mf][nf][r] + bb);
        *(us4*)(VTo + ((size_t)((bI*NHEAD + hh)*HD + dd))*SEQ + n0p) = o;
      }
    }
}

// ---------------- GEMM2: 64x128 tile, 768 blocks, 3-buf counted-vmcnt pipeline ------
__global__ __launch_bounds__(256, 4) void gemm2_bt(
    const unsigned short* __restrict__ A,
    const unsigned short* __restrict__ B,
    const float* __restrict__ bias,
    float* __restrict__ C)
{
  __shared__ __align__(16) char Al[3 * 4096];
  __shared__ __align__(16) char Bl[3 * 8192];

  const int tid  = threadIdx.x;
  const int lane = tid & 63;
  const int w    = tid >> 6;
  const int l15  = lane & 15;
  const int g    = lane >> 4;
  const int wm   = (w >> 1) * 32;
  const int wn   = (w & 1) * 64;

  const int id  = blockIdx.x;
  const int xcd = id & 7;
  const int j   = id >> 3;
  const int mi  = xcd * 16 + (j & 15);
  const int ni  = j >> 4;
  const int mbase = mi * 64;
  const int nbase = ni * 128;

  const int trow  = tid >> 2;
  const int sslot = ((tid & 3) ^ ((tid >> 3) & 3)) * 8;
  const unsigned short* Ag = A + (size_t)(mbase + trow) * 768 + sslot;
  const unsigned short* Bg = B + (size_t)(nbase + trow) * 768 + sslot;

  auto STAGE = [&](int buf, int t) {
    const unsigned short* sa = Ag + t * 32;
    const unsigned short* sb = Bg + t * 32;
    char* da = Al + buf * 4096 + tid * 16;
    char* db = Bl + buf * 8192 + tid * 16;
    gload_lds16(sa,           da);
    gload_lds16(sb,           db);
    gload_lds16(sb + 64*768,  db + 4096);
  };

  f32x4 acc[2][4] = {};

  STAGE(0, 0);
  STAGE(1, 1);
  asm volatile("s_waitcnt vmcnt(3)" ::: "memory");   // t=0 landed; t=1 in flight
  __builtin_amdgcn_s_barrier();

  for (int t = 0; t < 24; t++) {
    if (t < 22) STAGE((t + 2) % 3, t + 2);

    const char* Ab = Al + (t % 3) * 4096;
    const char* Bb = Bl + (t % 3) * 8192;
    bf16x8 af[2], bfv[4];
#pragma unroll
    for (int mf = 0; mf < 2; mf++) {
      const int row = wm + mf*16 + l15;
      af[mf] = *(const bf16x8*)(Ab + FOFF(row));
    }
#pragma unroll
    for (int nf = 0; nf < 4; nf++) {
      const int row = wn + nf*16 + l15;
      bfv[nf] = *(const bf16x8*)(Bb + FOFF(row));
    }
    __builtin_amdgcn_s_setprio(1);
#pragma unroll
    for (int mf = 0; mf < 2; mf++)
#pragma unroll
      for (int nf = 0; nf < 4; nf++)
        acc[mf][nf] = __builtin_amdgcn_mfma_f32_16x16x32_bf16(af[mf], bfv[nf], acc[mf][nf], 0, 0, 0);
    __builtin_amdgcn_s_setprio(0);

    if (t < 23) {
      if (t < 22) asm volatile("s_waitcnt vmcnt(3)" ::: "memory");
      else        asm volatile("s_waitcnt vmcnt(0)" ::: "memory");
      __builtin_amdgcn_s_barrier();
    }
  }

#pragma unroll
  for (int mf = 0; mf < 2; mf++)
#pragma unroll
    for (int nf = 0; nf < 4; nf++) {
      const int col  = nbase + wn + nf*16 + l15;
      const float bb = bias[col];
      const int row0 = mbase + wm + mf*16 + g*4;
#pragma unroll
      for (int r = 0; r < 4; r++)
        C[(size_t)(row0 + r)*FEATS + col] = acc[mf][nf][r] + bb;
    }
}
#undef FOFF

// ---------------- fused sigmoid attention v8: pipeline + permuted-V in-register S ----
// R1-verified pipeline (QK(t) || sigmoid+PV(t-1), V staged one tile behind K).
// S LDS round-trip ELIMINATED with zero cross-lane ops: V^T key columns were
// permuted at the GEMM1 producer (c(r) bit-permutation) so that the PV B-operand
// for (g, js) is exactly [sig(sT[2js][0..3]), sig(sT[2js+1][0..3])] of this lane.
// Derivation: QK^T D slot (nf,g,rr) = key nf*16+g*4+rr; PV B slot (js,g,j) = col
// js*32+g*8+j; producer places physical key r at col c = [b5|b3b2|b4|b1b0](r).
__global__ __launch_bounds__(256, 3) void attn_kernel(
    const unsigned short* __restrict__ QK,    // [8192][1536] (Q cols pre-scaled)
    const unsigned short* __restrict__ VT,    // [(b*12+h)*64 + d][1024], key-permuted
    const float* __restrict__ biasp,
    unsigned short* __restrict__ AO)          // [8192][768] bf16
{
  __shared__ __align__(16) char Kl[2][8192];   // [64 key][64 hd] bf16, XOR-swizzled
  __shared__ __align__(16) char Vl[2][8192];   // [64 d][64 keycol] bf16, XOR-swizzled

  const int tid  = threadIdx.x;
  const int lane = tid & 63;
  const int w    = tid >> 6;       // 0..3
  const int l15  = lane & 15;
  const int g    = lane >> 4;

  const int id  = blockIdx.x;
  const int r8  = id & 7;
  const int m   = id >> 3;
  const int bh  = r8 * 12 + (m >> 3);
  const int qx  = m & 7;
  const int b   = bh / NHEAD;
  const int h   = bh % NHEAD;
  const int rowB  = b * SEQ;
  const int qbase = rowB + qx * 128;

  const float Kb = __builtin_amdgcn_exp2f(-biasp[0] * 1.4426950408889634f);

  // Q fragments: qf[qm][ks], wave w rows [qbase+w*32+qm*16, +16)
  bf16x8 qf[2][2];
  {
    const unsigned short* qp = QK + (size_t)(qbase + w*32 + l15) * NQK + h*HD + g*8;
    qf[0][0] = *(const bf16x8*)(qp);
    qf[0][1] = *(const bf16x8*)(qp + 32);
    qf[1][0] = *(const bf16x8*)(qp + 16*NQK);
    qf[1][1] = *(const bf16x8*)(qp + 16*NQK + 32);
  }

  // staging: 256 thr x 16B = 4KB/issue; 2 issues per K tile (rows 0-31, 32-63), 2 per V
  const int trow = tid >> 3;                               // 0..31
  const int colb = ((tid & 7) * 16) ^ ((trow & 7) << 4);   // pre-swizzled source
  const char* Ksrc = (const char*)QK +
      ((size_t)(rowB + trow) * NQK + FEATS + h*HD) * 2 + colb;
  const char* Vsrc = (const char*)VT +
      ((size_t)(bh*HD + trow)) * (SEQ*2) + colb;

  auto STAGE_K = [&](int p, int t) {
    char* kw = Kl[p] + tid*16;
    gload_lds16(Ksrc + (size_t)t * 64 * (NQK*2),              kw);
    gload_lds16(Ksrc + (size_t)t * 64 * (NQK*2) + 32*(NQK*2), kw + 4096);
  };
  auto STAGE_V = [&](int p, int t) {
    char* vw = Vl[p] + tid*16;
    gload_lds16(Vsrc + t * 128,              vw);
    gload_lds16(Vsrc + t * 128 + 32*(SEQ*2), vw + 4096);
  };

  f32x4 o_acc[4][2] = {};
  f32x4 sE[2][4], sO[2][4];    // ping-pong score tiles (even/odd t)

  // sigmoid(prev scores) -> in-register bf16 B-frags (no cross-lane; V pre-permuted)
  auto SIGPV = [&](f32x4 (&sP)[2][4], const char* Vp) {
    bf16x8 paq[2][2];
#pragma unroll
    for (int qm = 0; qm < 2; qm++) {
      float sg[4][4];
#pragma unroll
      for (int nf = 0; nf < 4; nf++)
#pragma unroll
        for (int rr = 0; rr < 4; rr++) {
          const float e = __builtin_amdgcn_exp2f(-sP[qm][nf][rr]);
          sg[nf][rr] = __builtin_amdgcn_rcpf(__builtin_fmaf(Kb, e, 1.0f));
        }
#pragma unroll
      for (int js = 0; js < 2; js++) {
        bf16x8 pa;
#pragma unroll
        for (int jj = 0; jj < 4; jj++) {
          pa[jj]     = (__bf16)sg[2*js][jj];
          pa[jj + 4] = (__bf16)sg[2*js + 1][jj];
        }
        paq[qm][js] = pa;
      }
    }
#pragma unroll
    for (int js = 0; js < 2; js++) {
      bf16x8 vf[4];
#pragma unroll
      for (int df = 0; df < 4; df++) {
        const int row = df*16 + l15;
        const int by  = (row*128 + js*64 + g*16) ^ ((row & 7) << 4);
        vf[df] = *(const bf16x8*)(Vp + by);
      }
      __builtin_amdgcn_s_setprio(1);
#pragma unroll
      for (int df = 0; df < 4; df++)
#pragma unroll
        for (int qm = 0; qm < 2; qm++)
          o_acc[df][qm] = __builtin_amdgcn_mfma_f32_16x16x32_bf16(vf[df], paq[qm][js], o_acc[df][qm], 0, 0, 0);
      __builtin_amdgcn_s_setprio(0);
    }
  };

  // one pipeline stage: stage K(t+1),V(t); QK(t)->sC; sigmoid+PV of tile t-1; barrier
  auto BODY = [&](int t, f32x4 (&sC)[2][4], f32x4 (&sP)[2][4], bool stK, bool doPrev) {
    if (stK) STAGE_K((t + 1) & 1, t + 1);
    STAGE_V(t & 1, t);

    const char* Kp = Kl[t & 1];
#pragma unroll
    for (int qm = 0; qm < 2; qm++)
#pragma unroll
      for (int nf = 0; nf < 4; nf++)
        sC[qm][nf] = (f32x4){0.f, 0.f, 0.f, 0.f};
    __builtin_amdgcn_s_setprio(1);
#pragma unroll
    for (int nf = 0; nf < 4; nf++)
#pragma unroll
      for (int ks = 0; ks < 2; ks++) {
        const int row = nf*16 + l15;
        const int by  = (row*128 + ks*64 + g*16) ^ ((row & 7) << 4);
        bf16x8 kf = *(const bf16x8*)(Kp + by);
        sC[0][nf] = __builtin_amdgcn_mfma_f32_16x16x32_bf16(kf, qf[0][ks], sC[0][nf], 0, 0, 0);
        sC[1][nf] = __builtin_amdgcn_mfma_f32_16x16x32_bf16(kf, qf[1][ks], sC[1][nf], 0, 0, 0);
      }
    __builtin_amdgcn_s_setprio(0);

    if (doPrev) SIGPV(sP, Vl[(t - 1) & 1]);

    __syncthreads();
  };

  STAGE_K(0, 0);
  __syncthreads();

  BODY(0, sE, sO, true, false);          // QK(0); stage K(1),V(0)
#pragma unroll 1
  for (int t = 1; t < 15; t += 2) {
    BODY(t,     sO, sE, true, true);     // QK(t)  || sigmoid+PV(t-1)
    BODY(t + 1, sE, sO, true, true);
  }
  BODY(15, sO, sE, false, true);         // QK(15) || sigmoid+PV(14); stage V(15)
  SIGPV(sO, Vl[1]);                      // drain: sigmoid+PV(15)

  // ---- epilogue: o_acc[df][qm]: col=l15 -> q, row=df*16+g*4+rr -> d ----
  unsigned short* aop = AO + (size_t)(qbase + w*32) * FEATS + h*HD;
#pragma unroll
  for (int df = 0; df < 4; df++)
#pragma unroll
    for (int qm = 0; qm < 2; qm++) {
      const int q  = qm*16 + l15;
      const int d0 = df*16 + g*4;
      bf16x4 o;
#pragma unroll
      for (int rr = 0; rr < 4; rr++) o[rr] = (__bf16)o_acc[df][qm][rr];
      *(bf16x4*)(aop + (size_t)q * FEATS + d0) = o;
    }
}

// ---------------- launch ----------------
extern "C" void kernel_launch(void* const* d_in, const int* in_sizes, int n_in,
                              void* d_out, int out_size, void* d_ws, size_t ws_size,
                              hipStream_t stream) {
  const float* x    = (const float*)d_in[0];
  const float* bias = (const float*)d_in[1];
  const float* Wq   = (const float*)d_in[2];
  const float* bq   = (const float*)d_in[3];
  const float* Wk   = (const float*)d_in[4];
  const float* bk   = (const float*)d_in[5];
  const float* Wv   = (const float*)d_in[6];
  const float* bv   = (const float*)d_in[7];
  const float* Wo   = (const float*)d_in[8];
  const float* bo   = (const float*)d_in[9];
  float* out = (float*)d_out;

  char* ws = (char*)d_ws;
  unsigned short* Xbf  = (unsigned short*)(ws + 0);
  unsigned short* Wcat = (unsigned short*)(ws + 12582912);
  unsigned short* Wobf = (unsigned short*)(ws + 16121856);
  float*          bcat = (float*)        (ws + 17301504);
  unsigned short* QKb  = (unsigned short*)(ws + 17310720);
  unsigned short* VTb  = (unsigned short*)(ws + 42476544);
  unsigned short* AO   = Xbf;   // alias: Xbf dead after GEMM1

  cast_all<<<8457, 256, 0, stream>>>(x, Wq, Wk, Wv, Wo, bq, bk, bv,
                                     Xbf, Wcat, Wobf, bcat);

  gemm1_bt<<<768, 256, 0, stream>>>(Xbf, Wcat, bcat, QKb, VTb);

  attn_kernel<<<768, 256, 0, stream>>>(QKb, VTb, bias, AO);

  gemm2_bt<<<768, 256, 0, stream>>>(AO, Wobf, bo, out);
}

// Round 5
// 105.068 us; speedup vs baseline: 1.1243x; 1.1243x over previous
//
#include <hip/hip_runtime.h>

#define FEATS 768
#define NHEAD 12
#define HD    64
#define SEQ   1024
#define NB    8
#define MROWS (NB*SEQ)      // 8192
#define NQK   (2*FEATS)     // 1536
#define QKVN  (3*FEATS)     // 2304
#define QSC   0.0520616136f // (1/sqrt(768)) * log2(e), folded into Q at GEMM1 epilogue

typedef __attribute__((ext_vector_type(8))) __bf16          bf16x8;
typedef __attribute__((ext_vector_type(4))) __bf16          bf16x4;
typedef __attribute__((ext_vector_type(4))) unsigned short  us4;
typedef __attribute__((ext_vector_type(4))) float           f32x4;

__device__ __forceinline__ unsigned short f2bf(float f) {
  union { float f; unsigned u; } v; v.f = f;
  return (unsigned short)((v.u + 0x7fffu + ((v.u >> 16) & 1u)) >> 16);  // RNE
}

__device__ __forceinline__ void gload_lds16(const void* g, void* l) {
  __builtin_amdgcn_global_load_lds(
      (const __attribute__((address_space(1))) void*)g,
      (__attribute__((address_space(3))) void*)l, 16, 0, 0);
}

// ---------------- fused casts (at BW ceiling -- unchanged) ----------------
__global__ void cast_all(const float* __restrict__ x,
                         const float* __restrict__ Wq, const float* __restrict__ Wk,
                         const float* __restrict__ Wv, const float* __restrict__ Wo,
                         const float* __restrict__ bq, const float* __restrict__ bk,
                         const float* __restrict__ bv,
                         unsigned short* __restrict__ Xbf,
                         unsigned short* __restrict__ Wcat,
                         unsigned short* __restrict__ Wobf,
                         float* __restrict__ bcat) {
  int blk = blockIdx.x;
  if (blk < 6144) {
    int i = blk * 256 + threadIdx.x;
    f32x4 v = ((const f32x4*)x)[i];
    us4 o;
    o[0] = f2bf(v[0]); o[1] = f2bf(v[1]); o[2] = f2bf(v[2]); o[3] = f2bf(v[3]);
    ((us4*)Xbf)[i] = o;
  } else if (blk < 8448) {
    int bb = blk - 6144;
    int mtx = bb / 576;
    int i = (bb % 576) * 256 + threadIdx.x;
    const float* src = (mtx == 0) ? Wq : (mtx == 1) ? Wk : (mtx == 2) ? Wv : Wo;
    f32x4 v = ((const f32x4*)src)[i];
    us4 o;
    o[0] = f2bf(v[0]); o[1] = f2bf(v[1]); o[2] = f2bf(v[2]); o[3] = f2bf(v[3]);
    if (mtx < 3) ((us4*)Wcat)[mtx * 147456 + i] = o;
    else         ((us4*)Wobf)[i] = o;
  } else {
    int i = (blk - 8448) * 256 + threadIdx.x;
    if (i < QKVN)
      bcat[i] = (i < FEATS) ? bq[i] : (i < 2*FEATS ? bk[i-FEATS] : bv[i-2*FEATS]);
  }
}

// read-side LDS swizzle (R7-R10 measured: 0 bank conflicts)
#define FOFF(row) ((row)*64 + (((g) ^ (((row) >> 1) & 3)) << 4))

// ---------------- GEMM1: 128x192 tile, 768 blocks, asym A2/B3 counted-vmcnt --------
// QKV = Xbf * Wcat^T + bcat. ni 0..3 -> Q (pre-scaled by QSC), 4..7 -> K, 8..11 -> V^T.
// V^T key columns are PERMUTED within each 64-key tile (bit-permutation c(r)) so the
// attention PV B-operand needs no cross-lane redistribution (see attn_kernel).
// Pipeline: A double-buffered (stage t+1), B triple-buffered (stage t+2).
// Per iter: issue A(t+1)[2], B(t+2)[3]; compute; s_waitcnt vmcnt(3) -> oldest 5
// (B(t+1)+A(t+1)) landed, B(t+2)'s 3 stay in flight across the barrier.
// LDS = 2*8KB + 3*12KB = 53,248 B -> exactly 3 blocks/CU (occupancy preserved).
__global__ __launch_bounds__(256, 3) void gemm1_bt(
    const unsigned short* __restrict__ A,
    const unsigned short* __restrict__ B,
    const float* __restrict__ bias,
    unsigned short* __restrict__ QKo,
    unsigned short* __restrict__ VTo)
{
  __shared__ __align__(16) char Al[2 * 8192];    // [buf][128 rows][64B]
  __shared__ __align__(16) char Bl[3 * 12288];   // [buf][192 rows][64B]

  const int tid  = threadIdx.x;
  const int lane = tid & 63;
  const int w    = tid >> 6;
  const int l15  = lane & 15;
  const int g    = lane >> 4;
  const int wm   = (w >> 1) * 64;
  const int wn   = (w & 1) * 96;

  const int id  = blockIdx.x;            // 768 = 8 xcd * (8 mi * 12 ni)
  const int xcd = id & 7;
  const int j   = id >> 3;
  const int mi  = xcd * 8 + (j & 7);
  const int ni  = j >> 3;                // 0..11
  const int mbase = mi * 128;
  const int nbase = ni * 192;

  const int trow  = tid >> 2;
  const int sslot = ((tid & 3) ^ ((tid >> 3) & 3)) * 8;
  const unsigned short* Ag = A + (size_t)(mbase + trow) * 768 + sslot;
  const unsigned short* Bg = B + (size_t)(nbase + trow) * 768 + sslot;

  auto STAGE_A = [&](int buf, int t) {
    const unsigned short* sa = Ag + t * 32;
    char* da = Al + buf * 8192 + tid * 16;
    gload_lds16(sa,            da);
    gload_lds16(sa + 64*768,   da + 4096);
  };
  auto STAGE_B = [&](int buf, int t) {
    const unsigned short* sb = Bg + t * 32;
    char* db = Bl + buf * 12288 + tid * 16;
    gload_lds16(sb,            db);
    gload_lds16(sb + 64*768,   db + 4096);
    gload_lds16(sb + 128*768,  db + 8192);
  };

  f32x4 acc[4][6] = {};

  STAGE_A(0, 0);
  STAGE_B(0, 0);
  STAGE_B(1, 1);
  asm volatile("s_waitcnt vmcnt(3)" ::: "memory");   // A(0)+B(0) landed; B(1) in flight
  __builtin_amdgcn_s_barrier();

  for (int t = 0; t < 24; t++) {
    if (t < 23) STAGE_A((t + 1) & 1, t + 1);
    if (t < 22) STAGE_B((t + 2) % 3, t + 2);

    const char* Ab = Al + (t & 1) * 8192;
    const char* Bb = Bl + (t % 3) * 12288;
    bf16x8 af[4];
#pragma unroll
    for (int mf = 0; mf < 4; mf++) {
      const int row = wm + mf*16 + l15;
      af[mf] = *(const bf16x8*)(Ab + FOFF(row));
    }
    __builtin_amdgcn_s_setprio(1);
#pragma unroll
    for (int nf = 0; nf < 6; nf++) {
      const int row = wn + nf*16 + l15;
      bf16x8 bfv = *(const bf16x8*)(Bb + FOFF(row));
#pragma unroll
      for (int mf = 0; mf < 4; mf++)
        acc[mf][nf] = __builtin_amdgcn_mfma_f32_16x16x32_bf16(af[mf], bfv, acc[mf][nf], 0, 0, 0);
    }
    __builtin_amdgcn_s_setprio(0);

    if (t < 23) {
      if (t < 22) asm volatile("s_waitcnt vmcnt(3)" ::: "memory");  // B(t+2) rides over
      else        asm volatile("s_waitcnt vmcnt(0)" ::: "memory");  // final drain
      __builtin_amdgcn_s_barrier();
    }
  }

  // epilogue: D layout col = lane&15, row = (lane>>4)*4 + reg (m89-verified)
  const bool isQK = (ni < 8);            // block-uniform
  const float osc = (ni < 4) ? QSC : 1.0f;   // Q pre-scale (block-uniform)
#pragma unroll
  for (int mf = 0; mf < 4; mf++)
#pragma unroll
    for (int nf = 0; nf < 6; nf++) {
      const int col  = nbase + wn + nf*16 + l15;
      const float bb = bias[col];
      const int row0 = mbase + wm + mf*16 + g*4;
      if (isQK) {
#pragma unroll
        for (int r = 0; r < 4; r++)
          QKo[(size_t)(row0 + r)*NQK + col] = f2bf((acc[mf][nf][r] + bb) * osc);
      } else {
        const int c  = col - NQK;
        const int hh = c >> 6, dd = c & 63;
        const int bI = row0 >> 10, n0 = row0 & 1023;
        // key-column bit-permutation within the 64-key tile:
        // r = [b5b4=nf | b3b2=g | b1b0=rr] -> c = [b5 | b3b2 | b4 | b1b0]
        const int rl  = n0 & 63;   // rr bits are 0 here (n0 multiple of 4)
        const int cp  = ((rl >> 5) << 5) | (((rl >> 2) & 3) << 3) | (((rl >> 4) & 1) << 2);
        const int n0p = (n0 & ~63) | cp;
        us4 o;
#pragma unroll
        for (int r = 0; r < 4; r++) o[r] = f2bf(acc[mf][nf][r] + bb);
        *(us4*)(VTo + ((size_t)((bI*NHEAD + hh)*HD + dd))*SEQ + n0p) = o;
      }
    }
}

// ---------------- GEMM2: 64x128 tile, 768 blocks, asym A2/B3 counted-vmcnt ---------
// LDS = 2*4KB + 3*8KB = 32KB -> >=4 blocks/CU. Per iter: issue A(t+1)[1], B(t+2)[2];
// wait vmcnt(2) -> B(t+2) rides across the barrier.
__global__ __launch_bounds__(256, 4) void gemm2_bt(
    const unsigned short* __restrict__ A,
    const unsigned short* __restrict__ B,
    const float* __restrict__ bias,
    float* __restrict__ C)
{
  __shared__ __align__(16) char Al[2 * 4096];
  __shared__ __align__(16) char Bl[3 * 8192];

  const int tid  = threadIdx.x;
  const int lane = tid & 63;
  const int w    = tid >> 6;
  const int l15  = lane & 15;
  const int g    = lane >> 4;
  const int wm   = (w >> 1) * 32;
  const int wn   = (w & 1) * 64;

  const int id  = blockIdx.x;
  const int xcd = id & 7;
  const int j   = id >> 3;
  const int mi  = xcd * 16 + (j & 15);
  const int ni  = j >> 4;
  const int mbase = mi * 64;
  const int nbase = ni * 128;

  const int trow  = tid >> 2;
  const int sslot = ((tid & 3) ^ ((tid >> 3) & 3)) * 8;
  const unsigned short* Ag = A + (size_t)(mbase + trow) * 768 + sslot;
  const unsigned short* Bg = B + (size_t)(nbase + trow) * 768 + sslot;

  auto STAGE_A = [&](int buf, int t) {
    char* da = Al + buf * 4096 + tid * 16;
    gload_lds16(Ag + t * 32, da);
  };
  auto STAGE_B = [&](int buf, int t) {
    const unsigned short* sb = Bg + t * 32;
    char* db = Bl + buf * 8192 + tid * 16;
    gload_lds16(sb,           db);
    gload_lds16(sb + 64*768,  db + 4096);
  };

  f32x4 acc[2][4] = {};

  STAGE_A(0, 0);
  STAGE_B(0, 0);
  STAGE_B(1, 1);
  asm volatile("s_waitcnt vmcnt(2)" ::: "memory");   // A(0)+B(0) landed; B(1) in flight
  __builtin_amdgcn_s_barrier();

  for (int t = 0; t < 24; t++) {
    if (t < 23) STAGE_A((t + 1) & 1, t + 1);
    if (t < 22) STAGE_B((t + 2) % 3, t + 2);

    const char* Ab = Al + (t & 1) * 4096;
    const char* Bb = Bl + (t % 3) * 8192;
    bf16x8 af[2], bfv[4];
#pragma unroll
    for (int mf = 0; mf < 2; mf++) {
      const int row = wm + mf*16 + l15;
      af[mf] = *(const bf16x8*)(Ab + FOFF(row));
    }
#pragma unroll
    for (int nf = 0; nf < 4; nf++) {
      const int row = wn + nf*16 + l15;
      bfv[nf] = *(const bf16x8*)(Bb + FOFF(row));
    }
    __builtin_amdgcn_s_setprio(1);
#pragma unroll
    for (int mf = 0; mf < 2; mf++)
#pragma unroll
      for (int nf = 0; nf < 4; nf++)
        acc[mf][nf] = __builtin_amdgcn_mfma_f32_16x16x32_bf16(af[mf], bfv[nf], acc[mf][nf], 0, 0, 0);
    __builtin_amdgcn_s_setprio(0);

    if (t < 23) {
      if (t < 22) asm volatile("s_waitcnt vmcnt(2)" ::: "memory");
      else        asm volatile("s_waitcnt vmcnt(0)" ::: "memory");
      __builtin_amdgcn_s_barrier();
    }
  }

#pragma unroll
  for (int mf = 0; mf < 2; mf++)
#pragma unroll
    for (int nf = 0; nf < 4; nf++) {
      const int col  = nbase + wn + nf*16 + l15;
      const float bb = bias[col];
      const int row0 = mbase + wm + mf*16 + g*4;
#pragma unroll
      for (int r = 0; r < 4; r++)
        C[(size_t)(row0 + r)*FEATS + col] = acc[mf][nf][r] + bb;
    }
}
#undef FOFF

// ---------------- fused sigmoid attention v8: pipeline + permuted-V in-register S ----
// R1-verified pipeline (QK(t) || sigmoid+PV(t-1), V staged one tile behind K).
// S LDS round-trip ELIMINATED with zero cross-lane ops: V^T key columns were
// permuted at the GEMM1 producer (c(r) bit-permutation) so that the PV B-operand
// for (g, js) is exactly [sig(sT[2js][0..3]), sig(sT[2js+1][0..3])] of this lane.
// Derivation: QK^T D slot (nf,g,rr) = key nf*16+g*4+rr; PV B slot (js,g,j) = col
// js*32+g*8+j; producer places physical key r at col c = [b5|b3b2|b4|b1b0](r).
__global__ __launch_bounds__(256, 3) void attn_kernel(
    const unsigned short* __restrict__ QK,    // [8192][1536] (Q cols pre-scaled)
    const unsigned short* __restrict__ VT,    // [(b*12+h)*64 + d][1024], key-permuted
    const float* __restrict__ biasp,
    unsigned short* __restrict__ AO)          // [8192][768] bf16
{
  __shared__ __align__(16) char Kl[2][8192];   // [64 key][64 hd] bf16, XOR-swizzled
  __shared__ __align__(16) char Vl[2][8192];   // [64 d][64 keycol] bf16, XOR-swizzled

  const int tid  = threadIdx.x;
  const int lane = tid & 63;
  const int w    = tid >> 6;       // 0..3
  const int l15  = lane & 15;
  const int g    = lane >> 4;

  const int id  = blockIdx.x;
  const int r8  = id & 7;
  const int m   = id >> 3;
  const int bh  = r8 * 12 + (m >> 3);
  const int qx  = m & 7;
  const int b   = bh / NHEAD;
  const int h   = bh % NHEAD;
  const int rowB  = b * SEQ;
  const int qbase = rowB + qx * 128;

  const float Kb = __builtin_amdgcn_exp2f(-biasp[0] * 1.4426950408889634f);

  // Q fragments: qf[qm][ks], wave w rows [qbase+w*32+qm*16, +16)
  bf16x8 qf[2][2];
  {
    const unsigned short* qp = QK + (size_t)(qbase + w*32 + l15) * NQK + h*HD + g*8;
    qf[0][0] = *(const bf16x8*)(qp);
    qf[0][1] = *(const bf16x8*)(qp + 32);
    qf[1][0] = *(const bf16x8*)(qp + 16*NQK);
    qf[1][1] = *(const bf16x8*)(qp + 16*NQK + 32);
  }

  // staging: 256 thr x 16B = 4KB/issue; 2 issues per K tile (rows 0-31, 32-63), 2 per V
  const int trow = tid >> 3;                               // 0..31
  const int colb = ((tid & 7) * 16) ^ ((trow & 7) << 4);   // pre-swizzled source
  const char* Ksrc = (const char*)QK +
      ((size_t)(rowB + trow) * NQK + FEATS + h*HD) * 2 + colb;
  const char* Vsrc = (const char*)VT +
      ((size_t)(bh*HD + trow)) * (SEQ*2) + colb;

  auto STAGE_K = [&](int p, int t) {
    char* kw = Kl[p] + tid*16;
    gload_lds16(Ksrc + (size_t)t * 64 * (NQK*2),              kw);
    gload_lds16(Ksrc + (size_t)t * 64 * (NQK*2) + 32*(NQK*2), kw + 4096);
  };
  auto STAGE_V = [&](int p, int t) {
    char* vw = Vl[p] + tid*16;
    gload_lds16(Vsrc + t * 128,              vw);
    gload_lds16(Vsrc + t * 128 + 32*(SEQ*2), vw + 4096);
  };

  f32x4 o_acc[4][2] = {};
  f32x4 sE[2][4], sO[2][4];    // ping-pong score tiles (even/odd t)

  // sigmoid(prev scores) -> in-register bf16 B-frags (no cross-lane; V pre-permuted)
  auto SIGPV = [&](f32x4 (&sP)[2][4], const char* Vp) {
    bf16x8 paq[2][2];
#pragma unroll
    for (int qm = 0; qm < 2; qm++) {
      float sg[4][4];
#pragma unroll
      for (int nf = 0; nf < 4; nf++)
#pragma unroll
        for (int rr = 0; rr < 4; rr++) {
          const float e = __builtin_amdgcn_exp2f(-sP[qm][nf][rr]);
          sg[nf][rr] = __builtin_amdgcn_rcpf(__builtin_fmaf(Kb, e, 1.0f));
        }
#pragma unroll
      for (int js = 0; js < 2; js++) {
        bf16x8 pa;
#pragma unroll
        for (int jj = 0; jj < 4; jj++) {
          pa[jj]     = (__bf16)sg[2*js][jj];
          pa[jj + 4] = (__bf16)sg[2*js + 1][jj];
        }
        paq[qm][js] = pa;
      }
    }
#pragma unroll
    for (int js = 0; js < 2; js++) {
      bf16x8 vf[4];
#pragma unroll
      for (int df = 0; df < 4; df++) {
        const int row = df*16 + l15;
        const int by  = (row*128 + js*64 + g*16) ^ ((row & 7) << 4);
        vf[df] = *(const bf16x8*)(Vp + by);
      }
      __builtin_amdgcn_s_setprio(1);
#pragma unroll
      for (int df = 0; df < 4; df++)
#pragma unroll
        for (int qm = 0; qm < 2; qm++)
          o_acc[df][qm] = __builtin_amdgcn_mfma_f32_16x16x32_bf16(vf[df], paq[qm][js], o_acc[df][qm], 0, 0, 0);
      __builtin_amdgcn_s_setprio(0);
    }
  };

  // one pipeline stage: stage K(t+1),V(t); QK(t)->sC; sigmoid+PV of tile t-1; barrier
  auto BODY = [&](int t, f32x4 (&sC)[2][4], f32x4 (&sP)[2][4], bool stK, bool doPrev) {
    if (stK) STAGE_K((t + 1) & 1, t + 1);
    STAGE_V(t & 1, t);

    const char* Kp = Kl[t & 1];
#pragma unroll
    for (int qm = 0; qm < 2; qm++)
#pragma unroll
      for (int nf = 0; nf < 4; nf++)
        sC[qm][nf] = (f32x4){0.f, 0.f, 0.f, 0.f};
    __builtin_amdgcn_s_setprio(1);
#pragma unroll
    for (int nf = 0; nf < 4; nf++)
#pragma unroll
      for (int ks = 0; ks < 2; ks++) {
        const int row = nf*16 + l15;
        const int by  = (row*128 + ks*64 + g*16) ^ ((row & 7) << 4);
        bf16x8 kf = *(const bf16x8*)(Kp + by);
        sC[0][nf] = __builtin_amdgcn_mfma_f32_16x16x32_bf16(kf, qf[0][ks], sC[0][nf], 0, 0, 0);
        sC[1][nf] = __builtin_amdgcn_mfma_f32_16x16x32_bf16(kf, qf[1][ks], sC[1][nf], 0, 0, 0);
      }
    __builtin_amdgcn_s_setprio(0);

    if (doPrev) SIGPV(sP, Vl[(t - 1) & 1]);

    __syncthreads();
  };

  STAGE_K(0, 0);
  __syncthreads();

  BODY(0, sE, sO, true, false);          // QK(0); stage K(1),V(0)
#pragma unroll 1
  for (int t = 1; t < 15; t += 2) {
    BODY(t,     sO, sE, true, true);     // QK(t)  || sigmoid+PV(t-1)
    BODY(t + 1, sE, sO, true, true);
  }
  BODY(15, sO, sE, false, true);         // QK(15) || sigmoid+PV(14); stage V(15)
  SIGPV(sO, Vl[1]);                      // drain: sigmoid+PV(15)

  // ---- epilogue: o_acc[df][qm]: col=l15 -> q, row=df*16+g*4+rr -> d ----
  unsigned short* aop = AO + (size_t)(qbase + w*32) * FEATS + h*HD;
#pragma unroll
  for (int df = 0; df < 4; df++)
#pragma unroll
    for (int qm = 0; qm < 2; qm++) {
      const int q  = qm*16 + l15;
      const int d0 = df*16 + g*4;
      bf16x4 o;
#pragma unroll
      for (int rr = 0; rr < 4; rr++) o[rr] = (__bf16)o_acc[df][qm][rr];
      *(bf16x4*)(aop + (size_t)q * FEATS + d0) = o;
    }
}

// ---------------- launch ----------------
extern "C" void kernel_launch(void* const* d_in, const int* in_sizes, int n_in,
                              void* d_out, int out_size, void* d_ws, size_t ws_size,
                              hipStream_t stream) {
  const float* x    = (const float*)d_in[0];
  const float* bias = (const float*)d_in[1];
  const float* Wq   = (const float*)d_in[2];
  const float* bq   = (const float*)d_in[3];
  const float* Wk   = (const float*)d_in[4];
  const float* bk   = (const float*)d_in[5];
  const float* Wv   = (const float*)d_in[6];
  const float* bv   = (const float*)d_in[7];
  const float* Wo   = (const float*)d_in[8];
  const float* bo   = (const float*)d_in[9];
  float* out = (float*)d_out;

  char* ws = (char*)d_ws;
  unsigned short* Xbf  = (unsigned short*)(ws + 0);
  unsigned short* Wcat = (unsigned short*)(ws + 12582912);
  unsigned short* Wobf = (unsigned short*)(ws + 16121856);
  float*          bcat = (float*)        (ws + 17301504);
  unsigned short* QKb  = (unsigned short*)(ws + 17310720);
  unsigned short* VTb  = (unsigned short*)(ws + 42476544);
  unsigned short* AO   = Xbf;   // alias: Xbf dead after GEMM1

  cast_all<<<8457, 256, 0, stream>>>(x, Wq, Wk, Wv, Wo, bq, bk, bv,
                                     Xbf, Wcat, Wobf, bcat);

  gemm1_bt<<<768, 256, 0, stream>>>(Xbf, Wcat, bcat, QKb, VTb);

  attn_kernel<<<768, 256, 0, stream>>>(QKb, VTb, bias, AO);

  gemm2_bt<<<768, 256, 0, stream>>>(AO, Wobf, bo, out);
}